// Round 1
// baseline (9.674 us; speedup 1.0000x reference)
//
#include <hip/hip_runtime.h>
#include <hip/hip_bf16.h>

#define MF_BATCH 16384
#define MF_DIM 100
#define MF_MU 0.5f

// Wave-per-row: lanes 0..49 each load one float2 (8B) of the user row and
// feed row -> coalesced 400B segment per row. Butterfly/shfl_down reduce
// across the 64-lane wave, lane 0 adds biases + mu and writes.
__global__ __launch_bounds__(256) void Matrixfactorization_39350490366306_kernel(
    const int* __restrict__ users,
    const int* __restrict__ feeds,
    const float* __restrict__ user_latent,
    const float* __restrict__ feed_latent,
    const float* __restrict__ user_bias,
    const float* __restrict__ feed_bias,
    float* __restrict__ out,
    int batch) {
  const int gtid = blockIdx.x * blockDim.x + threadIdx.x;
  const int row  = gtid >> 6;          // one wave (64 lanes) per batch row
  const int lane = threadIdx.x & 63;
  if (row >= batch) return;

  const int u = users[row];
  const int f = feeds[row];

  float partial = 0.0f;
  if (lane < MF_DIM / 2) {  // 50 lanes * float2 = 100 floats = full row
    const float2 a = reinterpret_cast<const float2*>(
        user_latent + (size_t)u * MF_DIM)[lane];
    const float2 b = reinterpret_cast<const float2*>(
        feed_latent + (size_t)f * MF_DIM)[lane];
    partial = a.x * b.x + a.y * b.y;
  }

  // 64-lane wave reduction
  #pragma unroll
  for (int off = 32; off > 0; off >>= 1)
    partial += __shfl_down(partial, off, 64);

  if (lane == 0) {
    out[row] = partial + user_bias[u] + feed_bias[f] + MF_MU;
  }
}

extern "C" void kernel_launch(void* const* d_in, const int* in_sizes, int n_in,
                              void* d_out, int out_size, void* d_ws, size_t ws_size,
                              hipStream_t stream) {
  const int*   users       = (const int*)d_in[0];
  const int*   feeds       = (const int*)d_in[1];
  const float* user_latent = (const float*)d_in[2];
  const float* feed_latent = (const float*)d_in[3];
  const float* user_bias   = (const float*)d_in[4];
  const float* feed_bias   = (const float*)d_in[5];
  float* out = (float*)d_out;

  const int batch = in_sizes[0];               // 16384
  const int waves_per_block = 256 / 64;        // 4 rows per block
  const int grid = (batch + waves_per_block - 1) / waves_per_block;

  Matrixfactorization_39350490366306_kernel<<<grid, 256, 0, stream>>>(
      users, feeds, user_latent, feed_latent, user_bias, feed_bias, out, batch);
}

// Round 2
// 9.333 us; speedup vs baseline: 1.0365x; 1.0365x over previous
//
#include <hip/hip_runtime.h>
#include <hip/hip_bf16.h>

#define MF_DIM 100
#define MF_MU 0.5f

// Two rows per wave: half-wave (32 lanes) per row. Lanes 0..24 of each half
// load float4 (25*16B = 400B = full row, coalesced); idle lanes 25/26 carry
// the bias gathers so they issue in parallel with the latent loads and get
// folded into the same shfl_xor reduction. Row indices for the wave's two
// rows are loaded as one wave-uniform int2 -> scalar loads.
__global__ __launch_bounds__(256) void Matrixfactorization_39350490366306_kernel(
    const int* __restrict__ users,
    const int* __restrict__ feeds,
    const float* __restrict__ user_latent,
    const float* __restrict__ feed_latent,
    const float* __restrict__ user_bias,
    const float* __restrict__ feed_bias,
    float* __restrict__ out,
    int batch) {
  const int tid    = blockIdx.x * blockDim.x + threadIdx.x;
  const int wave   = tid >> 6;            // global wave id
  const int lane   = threadIdx.x & 63;
  const int half   = lane >> 5;           // 0: row 2w, 1: row 2w+1
  const int sublane = lane & 31;

  const int row0 = wave * 2;              // this wave's first row
  if (row0 >= batch) return;

  // wave-uniform int2 loads of the two row indices -> s_load
  const int2 uu = reinterpret_cast<const int2*>(users)[wave];
  const int2 ff = reinterpret_cast<const int2*>(feeds)[wave];
  const int u = half ? uu.y : uu.x;
  const int f = half ? ff.y : ff.x;

  float partial = 0.0f;
  if (sublane < MF_DIM / 4) {  // 25 lanes * float4 = 100 floats
    const float4 a = reinterpret_cast<const float4*>(
        user_latent + (size_t)u * MF_DIM)[sublane];
    const float4 b = reinterpret_cast<const float4*>(
        feed_latent + (size_t)f * MF_DIM)[sublane];
    partial = a.x * b.x + a.y * b.y + a.z * b.z + a.w * b.w;
  } else if (sublane == 25) {
    partial = user_bias[u];               // issued alongside latent loads
  } else if (sublane == 26) {
    partial = feed_bias[f];
  }

  // 32-lane (within-half) butterfly reduction
  #pragma unroll
  for (int off = 16; off > 0; off >>= 1)
    partial += __shfl_xor(partial, off, 64);

  if (sublane == 0) {
    out[row0 + half] = partial + MF_MU;
  }
}

extern "C" void kernel_launch(void* const* d_in, const int* in_sizes, int n_in,
                              void* d_out, int out_size, void* d_ws, size_t ws_size,
                              hipStream_t stream) {
  const int*   users       = (const int*)d_in[0];
  const int*   feeds       = (const int*)d_in[1];
  const float* user_latent = (const float*)d_in[2];
  const float* feed_latent = (const float*)d_in[3];
  const float* user_bias   = (const float*)d_in[4];
  const float* feed_bias   = (const float*)d_in[5];
  float* out = (float*)d_out;

  const int batch = in_sizes[0];              // 16384 (even)
  const int rows_per_block = 8;               // 4 waves * 2 rows
  const int grid = (batch + rows_per_block - 1) / rows_per_block;

  Matrixfactorization_39350490366306_kernel<<<grid, 256, 0, stream>>>(
      users, feeds, user_latent, feed_latent, user_bias, feed_bias, out, batch);
}